// Round 2
// baseline (531.764 us; speedup 1.0000x reference)
//
#include <hip/hip_runtime.h>

typedef unsigned short u16;
typedef __attribute__((ext_vector_type(8))) short short8;   // 8 x bf16 (4 VGPRs)
typedef __attribute__((ext_vector_type(4))) float f32x4;    // MFMA accumulator

__device__ __forceinline__ u16 f2bf(float f) {
  union { float f; unsigned u; } c; c.f = f;
  unsigned u = c.u;
  return (u16)((u + 0x7FFFu + ((u >> 16) & 1u)) >> 16);     // round-nearest-even
}

// async global->LDS, 16B per lane; LDS dest is wave-uniform base + lane*16
__device__ __forceinline__ void gload16(const u16* g, u16* l) {
  __builtin_amdgcn_global_load_lds(
      (const __attribute__((address_space(1))) void*)g,
      (__attribute__((address_space(3))) void*)l, 16, 0, 0);
}

// ---------------------------------------------------------------- prep kernels
__global__ __launch_bounds__(256) void cvt_x_kernel(const float* __restrict__ x,
                                                    u16* __restrict__ xb) {
  int i = blockIdx.x * 256 + threadIdx.x;          // grid sized exactly: 4194304/4
  float4 v = ((const float4*)x)[i];
  uint2 st;
  st.x = (unsigned)f2bf(v.x) | ((unsigned)f2bf(v.y) << 16);
  st.y = (unsigned)f2bf(v.z) | ((unsigned)f2bf(v.w) << 16);
  ((uint2*)xb)[i] = st;
}

// Wt[n][k] = bf16(W[k][n]); tiled through LDS so both sides are coalesced.
__global__ __launch_bounds__(256) void transp_kernel(const float* __restrict__ W,
                                                     u16* __restrict__ Wt, int NC) {
  __shared__ u16 tile[32][33];
  const int tx = threadIdx.x & 31, ty = threadIdx.x >> 5;   // 32 x 8
  const int n0 = blockIdx.x * 32, k0 = blockIdx.y * 32;
#pragma unroll
  for (int i = 0; i < 4; i++)
    tile[ty + i * 8][tx] = f2bf(W[(size_t)(k0 + ty + i * 8) * NC + n0 + tx]);
  __syncthreads();
#pragma unroll
  for (int i = 0; i < 4; i++)
    Wt[(size_t)(n0 + ty + i * 8) * 512 + k0 + tx] = tile[tx][ty + i * 8];
}

// ---------------------------------------------------------------- GEMM (K=512)
// m97 structure: BM=128 x BN tile, BK=64, 4 waves (2x2), global_load_lds width 16.
// MODE 0 (BN=128): QKV epilogue -> scatter q/k head-major, V transposed, +b_qkv
// MODE 1 (BN=64):  out-proj epilogue -> fp32 out, +b_o
template<int MODE, int BN>
__global__ __launch_bounds__(256) void gemm_kernel(
    const u16* __restrict__ A, const u16* __restrict__ Bt,
    const float* __restrict__ biasv,
    u16* __restrict__ qb, u16* __restrict__ kb, u16* __restrict__ vtb,
    float* __restrict__ outp) {
  constexpr int BM = 128;
  constexpr int NI = BN / 32;                 // acc tiles per wave in n
  __shared__ u16 As[BM * 64];
  __shared__ u16 Bs[BN * 64];
  const int tid = threadIdx.x;
  const int lane = tid & 63;
  const int w = tid >> 6, wm = w >> 1, wn = w & 1;
  const int m0 = blockIdx.y * BM, n0 = blockIdx.x * BN;
  const int lm = lane & 15, lg = lane >> 4;
  const int sr = tid >> 3, sc = (tid & 7) * 8;  // staging: thread tid -> row sr(+32c), col sc
  f32x4 acc[4][NI] = {};

  for (int k0 = 0; k0 < 512; k0 += 64) {
    __syncthreads();                          // previous tile's reads done
#pragma unroll
    for (int c = 0; c < BM / 32; c++)
      gload16(&A[(size_t)(m0 + sr + c * 32) * 512 + k0 + sc], &As[c * 2048 + w * 512]);
#pragma unroll
    for (int c = 0; c < BN / 32; c++)
      gload16(&Bt[(size_t)(n0 + sr + c * 32) * 512 + k0 + sc], &Bs[c * 2048 + w * 512]);
    __syncthreads();                          // implicit vmcnt(0): tiles landed
#pragma unroll
    for (int tc = 0; tc < 2; tc++) {
      short8 bf[NI];
#pragma unroll
      for (int ni = 0; ni < NI; ni++)
        bf[ni] = *(const short8*)&Bs[(wn * (BN / 2) + ni * 16 + lm) * 64 + tc * 32 + lg * 8];
#pragma unroll
      for (int mi = 0; mi < 4; mi++) {
        short8 af = *(const short8*)&As[(wm * 64 + mi * 16 + lm) * 64 + tc * 32 + lg * 8];
#pragma unroll
        for (int ni = 0; ni < NI; ni++)
          acc[mi][ni] = __builtin_amdgcn_mfma_f32_16x16x32_bf16(af, bf[ni], acc[mi][ni], 0, 0, 0);
      }
    }
  }

#pragma unroll
  for (int mi = 0; mi < 4; mi++)
#pragma unroll
    for (int ni = 0; ni < NI; ni++) {
      const int col = n0 + wn * (BN / 2) + ni * 16 + lm;
      const float bv = biasv[col];
#pragma unroll
      for (int r2 = 0; r2 < 4; r2++) {
        const int row = m0 + wm * 64 + mi * 16 + lg * 4 + r2;  // C/D: col=lane&15, row=(lane>>4)*4+reg
        const float v = acc[mi][ni][r2] + bv;
        if (MODE == 0) {
          const int hh = col / 192, rem = col % 192;  // qkv reshape: col = h*192 + which*64 + t
          const int which = rem >> 6, t = rem & 63;
          const int b = row >> 10, n = row & 1023;
          const u16 bb = f2bf(v);
          if (which == 0)      qb[((size_t)(b * 8 + hh) * 1024 + n) * 64 + t] = bb;
          else if (which == 1) kb[((size_t)(b * 8 + hh) * 1024 + n) * 64 + t] = bb;
          else                 vtb[((size_t)(b * 8 + hh) * 64 + t) * 1024 + n] = bb;
        } else {
          outp[(size_t)row * 512 + col] = v;
        }
      }
    }
}

// ---------------------------------------------------------------- attention
// grid (N/16, B) = (64, 8) -> 512 blocks = 2 blocks/CU (16 waves/CU).
// block 512 = 8 waves; wave h = head h; 16 q-rows per block.
// Bias double-buffered in LDS, ONE barrier per 32-key chunk; register prefetch
// never crosses a barrier (so the barrier's vmcnt(0) drain can't serialize it).
// Softmax: exp2 domain, per-lane partial l (cross-lane reduce once at end),
// exact skip of the alpha-rescale when the running max didn't grow.
__global__ __launch_bounds__(512, 4) void attn_kernel(
    const u16* __restrict__ qb, const u16* __restrict__ kb,
    const u16* __restrict__ vtb, const float* __restrict__ bias,
    u16* __restrict__ yb) {
  __shared__ float biasS[2 * 8 * 16 * 34];   // [buf][h][q16][k32 + pad2] = 34,816 B
  __shared__ u16 Ps[8 * 16 * 40];            // per-wave P tile, 10,240 B
  const int tid = threadIdx.x;
  const int lane = tid & 63;
  const int h = tid >> 6;
  const int b = blockIdx.y;
  const int q0 = blockIdx.x * 16;
  const size_t bh = (size_t)b * 8 + h;
  const u16* Q  = qb  + bh * (1024 * 64);
  const u16* K  = kb  + bh * (1024 * 64);
  const u16* VT = vtb + bh * (64 * 1024);
  const int lm = lane & 15, lg = lane >> 4;

  // Q fragments in registers for the whole kernel (A-layout: m=lane&15, k=lg*8+j)
  short8 aq[2];
#pragma unroll
  for (int tc = 0; tc < 2; tc++)
    aq[tc] = *(const short8*)&Q[(size_t)(q0 + lm) * 64 + tc * 32 + lg * 8];

  f32x4 o[4] = {};
  float mrow[4], psum[4];
#pragma unroll
  for (int r2 = 0; r2 < 4; r2++) { mrow[r2] = -1e30f; psum[r2] = 0.f; }

  const float SC   = 0.125f * 1.4426950408889634f;  // 1/sqrt(64) * log2(e)
  const float LG2E = 1.4426950408889634f;

  // bias staging coords: wave h loads q-rows {h, h+8}; lane covers (k, h-half)
  const int kl = lane >> 1, h4 = (lane & 1) * 4;
  const size_t brow = (size_t)(b * 1024 + q0);

  // prologue: stage chunk 0 into buffer 0
#pragma unroll
  for (int rr = 0; rr < 2; rr++) {
    const int qr = h + rr * 8;
    float4 p0 = *(const float4*)&bias[((brow + qr) * 1024 + kl) * 8 + h4];
    biasS[(h4 + 0) * 544 + qr * 34 + kl] = p0.x;
    biasS[(h4 + 1) * 544 + qr * 34 + kl] = p0.y;
    biasS[(h4 + 2) * 544 + qr * 34 + kl] = p0.z;
    biasS[(h4 + 3) * 544 + qr * 34 + kl] = p0.w;
  }
  __syncthreads();

  for (int it = 0; it < 32; it++) {
    const int kc = it * 32;
    const int bb = (it & 1) * 4352;

    // prefetch next bias chunk into registers (in flight during this chunk's compute)
    float4 pre[2];
    const bool havePre = (it < 31);
    if (havePre) {
#pragma unroll
      for (int rr = 0; rr < 2; rr++) {
        const int qr = h + rr * 8;
        pre[rr] = *(const float4*)&bias[((brow + qr) * 1024 + kc + 32 + kl) * 8 + h4];
      }
    }

    // S = Q * K^T  (B-layout: n=lane&15 -> key, k=lg*8+j -> t)
    f32x4 sf[2];
    __builtin_amdgcn_s_setprio(1);
#pragma unroll
    for (int kt = 0; kt < 2; kt++) {
      short8 bk0 = *(const short8*)&K[(size_t)(kc + kt * 16 + lm) * 64 + lg * 8];
      short8 bk1 = *(const short8*)&K[(size_t)(kc + kt * 16 + lm) * 64 + 32 + lg * 8];
      f32x4 c = {0.f, 0.f, 0.f, 0.f};
      c = __builtin_amdgcn_mfma_f32_16x16x32_bf16(aq[0], bk0, c, 0, 0, 0);
      c = __builtin_amdgcn_mfma_f32_16x16x32_bf16(aq[1], bk1, c, 0, 0, 0);
      sf[kt] = c;
    }
    __builtin_amdgcn_s_setprio(0);

    // V rows for PV: issue early so L2 latency hides under the softmax VALU
    short8 bv[4];
#pragma unroll
    for (int nt = 0; nt < 4; nt++)
      bv[nt] = *(const short8*)&VT[(size_t)(nt * 16 + lm) * 1024 + kc + lg * 8];

    // online softmax (base-2 domain)
    float pv2[2][4];
#pragma unroll
    for (int kt = 0; kt < 2; kt++)
#pragma unroll
      for (int r2 = 0; r2 < 4; r2++)
        pv2[kt][r2] = sf[kt][r2] * SC +
                      biasS[bb + h * 544 + (lg * 4 + r2) * 34 + kt * 16 + lm] * LG2E;
    float rmax[4];
#pragma unroll
    for (int r2 = 0; r2 < 4; r2++) rmax[r2] = fmaxf(pv2[0][r2], pv2[1][r2]);
#pragma unroll
    for (int d = 1; d < 16; d <<= 1)
#pragma unroll
      for (int r2 = 0; r2 < 4; r2++)
        rmax[r2] = fmaxf(rmax[r2], __shfl_xor(rmax[r2], d));
    const float g = fmaxf(fmaxf(rmax[0] - mrow[0], rmax[1] - mrow[1]),
                          fmaxf(rmax[2] - mrow[2], rmax[3] - mrow[3]));
    if (!__all(g <= 0.f)) {            // exact: skip only when alpha == 1 for all rows
#pragma unroll
      for (int r2 = 0; r2 < 4; r2++) {
        const float mn = fmaxf(mrow[r2], rmax[r2]);
        const float al = exp2f(mrow[r2] - mn);
        mrow[r2] = mn;
        psum[r2] *= al;
#pragma unroll
        for (int nt = 0; nt < 4; nt++) o[nt][r2] *= al;
      }
    }
#pragma unroll
    for (int kt = 0; kt < 2; kt++)
#pragma unroll
      for (int r2 = 0; r2 < 4; r2++) {
        const float p = exp2f(pv2[kt][r2] - mrow[r2]);
        psum[r2] += p;                 // per-lane partial; reduced once after the loop
        Ps[h * 640 + (lg * 4 + r2) * 40 + kt * 16 + lm] = f2bf(p);
      }

    // PV: A = P (per-wave LDS round-trip, DS ops in order -> no barrier)
    short8 ap = *(const short8*)&Ps[h * 640 + lm * 40 + lg * 8];
    __builtin_amdgcn_s_setprio(1);
#pragma unroll
    for (int nt = 0; nt < 4; nt++)
      o[nt] = __builtin_amdgcn_mfma_f32_16x16x32_bf16(ap, bv[nt], o[nt], 0, 0, 0);
    __builtin_amdgcn_s_setprio(0);

    // stage the prefetched chunk into the other buffer; single barrier per chunk
    if (havePre) {
      const int nb = ((it + 1) & 1) * 4352;
#pragma unroll
      for (int rr = 0; rr < 2; rr++) {
        const int qr = h + rr * 8;
        biasS[nb + (h4 + 0) * 544 + qr * 34 + kl] = pre[rr].x;
        biasS[nb + (h4 + 1) * 544 + qr * 34 + kl] = pre[rr].y;
        biasS[nb + (h4 + 2) * 544 + qr * 34 + kl] = pre[rr].z;
        biasS[nb + (h4 + 3) * 544 + qr * 34 + kl] = pre[rr].w;
      }
      __syncthreads();
    }
  }

  // epilogue: reduce l across the 16-lane k-groups once, then y = O / l
  float lr[4];
#pragma unroll
  for (int r2 = 0; r2 < 4; r2++) {
    float s = psum[r2];
#pragma unroll
    for (int d = 1; d < 16; d <<= 1) s += __shfl_xor(s, d);
    lr[r2] = s;
  }
#pragma unroll
  for (int nt = 0; nt < 4; nt++)
#pragma unroll
    for (int r2 = 0; r2 < 4; r2++) {
      const int row = q0 + lg * 4 + r2;
      yb[((size_t)(b * 1024 + row)) * 512 + h * 64 + nt * 16 + lm] = f2bf(o[nt][r2] / lr[r2]);
    }
}

// ---------------------------------------------------------------- launch
extern "C" void kernel_launch(void* const* d_in, const int* in_sizes, int n_in,
                              void* d_out, int out_size, void* d_ws, size_t ws_size,
                              hipStream_t stream) {
  const float* x    = (const float*)d_in[0];
  const float* bias = (const float*)d_in[1];
  const float* Wqkv = (const float*)d_in[2];
  const float* bqkv = (const float*)d_in[3];
  const float* Wo   = (const float*)d_in[4];
  const float* bo   = (const float*)d_in[5];
  float* out = (float*)d_out;

  char* p = (char*)d_ws;
  u16* xb    = (u16*)p; p += (size_t)8192 * 512 * 2;        // 8 MB
  u16* wqkvT = (u16*)p; p += (size_t)1536 * 512 * 2;        // 1.5 MB
  u16* woT   = (u16*)p; p += (size_t)512 * 512 * 2;         // 0.5 MB
  u16* qB    = (u16*)p; p += (size_t)8 * 8 * 1024 * 64 * 2; // 8 MB
  u16* kB    = (u16*)p; p += (size_t)8 * 8 * 1024 * 64 * 2; // 8 MB
  u16* vtB   = (u16*)p; p += (size_t)8 * 8 * 64 * 1024 * 2; // 8 MB
  u16* yB    = (u16*)p; p += (size_t)8192 * 512 * 2;        // 8 MB  (total ~44 MB)

  cvt_x_kernel<<<4096, 256, 0, stream>>>(x, xb);
  transp_kernel<<<dim3(48, 16), 256, 0, stream>>>(Wqkv, wqkvT, 1536);
  transp_kernel<<<dim3(16, 16), 256, 0, stream>>>(Wo, woT, 512);
  gemm_kernel<0, 128><<<dim3(12, 64), 256, 0, stream>>>(xb, wqkvT, bqkv, qB, kB, vtB, nullptr);
  attn_kernel<<<dim3(64, 8), 512, 0, stream>>>(qB, kB, vtB, bias, yB);
  gemm_kernel<1, 64><<<dim3(8, 64), 256, 0, stream>>>(yB, woT, bo, nullptr, nullptr, nullptr, out);
}

// Round 5
// 512.410 us; speedup vs baseline: 1.0378x; 1.0378x over previous
//
#include <hip/hip_runtime.h>

typedef unsigned short u16;
typedef __attribute__((ext_vector_type(8))) short short8;   // 8 x bf16 (4 VGPRs)
typedef __attribute__((ext_vector_type(4))) float f32x4;    // MFMA accumulator / native float4

__device__ __forceinline__ u16 f2bf(float f) {
  union { float f; unsigned u; } c; c.f = f;
  unsigned u = c.u;
  return (u16)((u + 0x7FFFu + ((u >> 16) & 1u)) >> 16);     // round-nearest-even
}

// async global->LDS, 16B per lane; LDS dest is wave-uniform base + lane*16
__device__ __forceinline__ void gload16(const u16* g, u16* l) {
  __builtin_amdgcn_global_load_lds(
      (const __attribute__((address_space(1))) void*)g,
      (__attribute__((address_space(3))) void*)l, 16, 0, 0);
}

// ---------------------------------------------------------------- prep kernels
__global__ __launch_bounds__(256) void cvt_x_kernel(const float* __restrict__ x,
                                                    u16* __restrict__ xb) {
  int i = blockIdx.x * 256 + threadIdx.x;          // grid sized exactly: 4194304/4
  float4 v = ((const float4*)x)[i];
  uint2 st;
  st.x = (unsigned)f2bf(v.x) | ((unsigned)f2bf(v.y) << 16);
  st.y = (unsigned)f2bf(v.z) | ((unsigned)f2bf(v.w) << 16);
  ((uint2*)xb)[i] = st;
}

// Wt[n][k] = bf16(W[k][n]); tiled through LDS so both sides are coalesced.
__global__ __launch_bounds__(256) void transp_kernel(const float* __restrict__ W,
                                                     u16* __restrict__ Wt, int NC) {
  __shared__ u16 tile[32][33];
  const int tx = threadIdx.x & 31, ty = threadIdx.x >> 5;   // 32 x 8
  const int n0 = blockIdx.x * 32, k0 = blockIdx.y * 32;
#pragma unroll
  for (int i = 0; i < 4; i++)
    tile[ty + i * 8][tx] = f2bf(W[(size_t)(k0 + ty + i * 8) * NC + n0 + tx]);
  __syncthreads();
#pragma unroll
  for (int i = 0; i < 4; i++)
    Wt[(size_t)(n0 + ty + i * 8) * 512 + k0 + tx] = tile[tx][ty + i * 8];
}

// ---------------------------------------------------------------- GEMM (K=512)
// m97 structure: BM=128 x BN tile, BK=64, 4 waves (2x2), global_load_lds width 16.
// MODE 0 (BN=128): QKV epilogue -> scatter q/k head-major, V transposed, +b_qkv
// MODE 1 (BN=64):  out-proj epilogue -> fp32 out, +b_o
template<int MODE, int BN>
__global__ __launch_bounds__(256) void gemm_kernel(
    const u16* __restrict__ A, const u16* __restrict__ Bt,
    const float* __restrict__ biasv,
    u16* __restrict__ qb, u16* __restrict__ kb, u16* __restrict__ vtb,
    float* __restrict__ outp) {
  constexpr int BM = 128;
  constexpr int NI = BN / 32;                 // acc tiles per wave in n
  __shared__ u16 As[BM * 64];
  __shared__ u16 Bs[BN * 64];
  const int tid = threadIdx.x;
  const int lane = tid & 63;
  const int w = tid >> 6, wm = w >> 1, wn = w & 1;
  const int m0 = blockIdx.y * BM, n0 = blockIdx.x * BN;
  const int lm = lane & 15, lg = lane >> 4;
  const int sr = tid >> 3, sc = (tid & 7) * 8;  // staging: thread tid -> row sr(+32c), col sc
  f32x4 acc[4][NI] = {};

  for (int k0 = 0; k0 < 512; k0 += 64) {
    __syncthreads();                          // previous tile's reads done
#pragma unroll
    for (int c = 0; c < BM / 32; c++)
      gload16(&A[(size_t)(m0 + sr + c * 32) * 512 + k0 + sc], &As[c * 2048 + w * 512]);
#pragma unroll
    for (int c = 0; c < BN / 32; c++)
      gload16(&Bt[(size_t)(n0 + sr + c * 32) * 512 + k0 + sc], &Bs[c * 2048 + w * 512]);
    __syncthreads();                          // implicit vmcnt(0): tiles landed
#pragma unroll
    for (int tc = 0; tc < 2; tc++) {
      short8 bf[NI];
#pragma unroll
      for (int ni = 0; ni < NI; ni++)
        bf[ni] = *(const short8*)&Bs[(wn * (BN / 2) + ni * 16 + lm) * 64 + tc * 32 + lg * 8];
#pragma unroll
      for (int mi = 0; mi < 4; mi++) {
        short8 af = *(const short8*)&As[(wm * 64 + mi * 16 + lm) * 64 + tc * 32 + lg * 8];
#pragma unroll
        for (int ni = 0; ni < NI; ni++)
          acc[mi][ni] = __builtin_amdgcn_mfma_f32_16x16x32_bf16(af, bf[ni], acc[mi][ni], 0, 0, 0);
      }
    }
  }

#pragma unroll
  for (int mi = 0; mi < 4; mi++)
#pragma unroll
    for (int ni = 0; ni < NI; ni++) {
      const int col = n0 + wn * (BN / 2) + ni * 16 + lm;
      const float bv = biasv[col];
#pragma unroll
      for (int r2 = 0; r2 < 4; r2++) {
        const int row = m0 + wm * 64 + mi * 16 + lg * 4 + r2;  // C/D: col=lane&15, row=(lane>>4)*4+reg
        const float v = acc[mi][ni][r2] + bv;
        if (MODE == 0) {
          const int hh = col / 192, rem = col % 192;  // qkv reshape: col = h*192 + which*64 + t
          const int which = rem >> 6, t = rem & 63;
          const int b = row >> 10, n = row & 1023;
          const u16 bb = f2bf(v);
          if (which == 0)      qb[((size_t)(b * 8 + hh) * 1024 + n) * 64 + t] = bb;
          else if (which == 1) kb[((size_t)(b * 8 + hh) * 1024 + n) * 64 + t] = bb;
          else                 vtb[((size_t)(b * 8 + hh) * 64 + t) * 1024 + n] = bb;
        } else {
          outp[(size_t)row * 512 + col] = v;
        }
      }
    }
}

// ---------------------------------------------------------------- attention
// grid (64, 8) = 512 blocks, XCD-affine: b = linear%8 so all 64 q-blocks of a
// batch share one XCD -> K/V (2 MB/batch) is L2-resident (the 1 GB of K/V
// re-reads was the hidden cost; FETCH_SIZE only showed the bias stream).
// Bias: 2-deep register prefetch + raw s_barrier with lgkmcnt-only drain, so
// bias loads stay in flight ACROSS barriers (no vmcnt(0) drain per iter).
// Bias loads are non-temporal: single-touch stream, don't evict K/V from L2.
__global__ __launch_bounds__(512, 4) void attn_kernel(
    const u16* __restrict__ qb, const u16* __restrict__ kb,
    const u16* __restrict__ vtb, const float* __restrict__ bias,
    u16* __restrict__ yb) {
  __shared__ float biasS[2 * 4352];          // [buf][h8][q16][k32 + pad2] = 34,816 B
  __shared__ u16 Ps[8 * 16 * 40];            // per-wave P tile, 10,240 B
  const int tid = threadIdx.x;
  const int lane = tid & 63;
  const int h = tid >> 6;
  const int linear = blockIdx.x + (blockIdx.y << 6);   // gridDim = (64, 8)
  const int b = linear & 7;                            // XCD-affine batch
  const int q0 = (linear >> 3) * 16;
  const size_t bh = (size_t)b * 8 + h;
  const u16* Q  = qb  + bh * (1024 * 64);
  const u16* K  = kb  + bh * (1024 * 64);
  const u16* VT = vtb + bh * (64 * 1024);
  const int lm = lane & 15, lg = lane >> 4;

  // Q fragments in registers for the whole kernel (A-layout: m=lane&15, k=lg*8+j)
  short8 aq[2];
#pragma unroll
  for (int tc = 0; tc < 2; tc++)
    aq[tc] = *(const short8*)&Q[(size_t)(q0 + lm) * 64 + tc * 32 + lg * 8];

  f32x4 o[4] = {};
  float mrow[4], psum[4];
#pragma unroll
  for (int r2 = 0; r2 < 4; r2++) { mrow[r2] = -1e30f; psum[r2] = 0.f; }

  const float SC   = 0.125f * 1.4426950408889634f;  // 1/sqrt(64) * log2(e)
  const float LG2E = 1.4426950408889634f;

  // bias staging coords: wave h loads q-rows {h, h+8}; lane covers (k, h-half)
  const int kl = lane >> 1, h4 = (lane & 1) * 4;
  const size_t brow = (size_t)(b * 1024 + q0);

  auto loadPre = [&](int chunk, f32x4* pre) {
#pragma unroll
    for (int rr = 0; rr < 2; rr++) {
      const int qr = h + rr * 8;
      pre[rr] = __builtin_nontemporal_load(
          (const f32x4*)&bias[((brow + qr) * 1024 + chunk * 32 + kl) * 8 + h4]);
    }
  };
  auto writePre = [&](const f32x4* pre, int nb) {
#pragma unroll
    for (int rr = 0; rr < 2; rr++) {
      const int qr = h + rr * 8;
      biasS[nb + (h4 + 0) * 544 + qr * 34 + kl] = pre[rr][0];
      biasS[nb + (h4 + 1) * 544 + qr * 34 + kl] = pre[rr][1];
      biasS[nb + (h4 + 2) * 544 + qr * 34 + kl] = pre[rr][2];
      biasS[nb + (h4 + 3) * 544 + qr * 34 + kl] = pre[rr][3];
    }
  };
  // barrier that drains LDS ops only -- vmcnt (bias prefetch) stays in flight
  auto barrier = [&]() {
    asm volatile("s_waitcnt lgkmcnt(0)" ::: "memory");
    __builtin_amdgcn_s_barrier();
    __builtin_amdgcn_sched_barrier(0);
  };

  auto compute = [&](int it) {
    const int kc = it * 32;
    const int bbS = (it & 1) * 4352;

    // S = Q * K^T  (B-layout: n=lane&15 -> key, k=lg*8+j -> t)
    f32x4 sf[2];
    __builtin_amdgcn_s_setprio(1);
#pragma unroll
    for (int kt = 0; kt < 2; kt++) {
      short8 bk0 = *(const short8*)&K[(size_t)(kc + kt * 16 + lm) * 64 + lg * 8];
      short8 bk1 = *(const short8*)&K[(size_t)(kc + kt * 16 + lm) * 64 + 32 + lg * 8];
      f32x4 c = {0.f, 0.f, 0.f, 0.f};
      c = __builtin_amdgcn_mfma_f32_16x16x32_bf16(aq[0], bk0, c, 0, 0, 0);
      c = __builtin_amdgcn_mfma_f32_16x16x32_bf16(aq[1], bk1, c, 0, 0, 0);
      sf[kt] = c;
    }
    __builtin_amdgcn_s_setprio(0);

    // V rows for PV: issue early so L2 latency hides under the softmax VALU
    short8 bv[4];
#pragma unroll
    for (int nt = 0; nt < 4; nt++)
      bv[nt] = *(const short8*)&VT[(size_t)(nt * 16 + lm) * 1024 + kc + lg * 8];

    // online softmax (base-2 domain)
    float pv2[2][4];
#pragma unroll
    for (int kt = 0; kt < 2; kt++)
#pragma unroll
      for (int r2 = 0; r2 < 4; r2++)
        pv2[kt][r2] = sf[kt][r2] * SC +
                      biasS[bbS + h * 544 + (lg * 4 + r2) * 34 + kt * 16 + lm] * LG2E;
    float rmax[4];
#pragma unroll
    for (int r2 = 0; r2 < 4; r2++) rmax[r2] = fmaxf(pv2[0][r2], pv2[1][r2]);
#pragma unroll
    for (int d = 1; d < 16; d <<= 1)
#pragma unroll
      for (int r2 = 0; r2 < 4; r2++)
        rmax[r2] = fmaxf(rmax[r2], __shfl_xor(rmax[r2], d));
    const float g = fmaxf(fmaxf(rmax[0] - mrow[0], rmax[1] - mrow[1]),
                          fmaxf(rmax[2] - mrow[2], rmax[3] - mrow[3]));
    if (!__all(g <= 0.f)) {            // exact: skip only when alpha == 1 for all rows
#pragma unroll
      for (int r2 = 0; r2 < 4; r2++) {
        const float mn = fmaxf(mrow[r2], rmax[r2]);
        const float al = exp2f(mrow[r2] - mn);
        mrow[r2] = mn;
        psum[r2] *= al;
#pragma unroll
        for (int nt = 0; nt < 4; nt++) o[nt][r2] *= al;
      }
    }
#pragma unroll
    for (int kt = 0; kt < 2; kt++)
#pragma unroll
      for (int r2 = 0; r2 < 4; r2++) {
        const float p = exp2f(pv2[kt][r2] - mrow[r2]);
        psum[r2] += p;                 // per-lane partial; reduced once after the loop
        Ps[h * 640 + (lg * 4 + r2) * 40 + kt * 16 + lm] = f2bf(p);
      }

    // PV: A = P (per-wave LDS round-trip, DS ops in order -> no barrier)
    short8 ap = *(const short8*)&Ps[h * 640 + lm * 40 + lg * 8];
    __builtin_amdgcn_s_setprio(1);
#pragma unroll
    for (int nt = 0; nt < 4; nt++)
      o[nt] = __builtin_amdgcn_mfma_f32_16x16x32_bf16(ap, bv[nt], o[nt], 0, 0, 0);
    __builtin_amdgcn_s_setprio(0);
  };

  // prologue: chunk0 -> LDS buf0; chunk1 in flight in preA
  f32x4 preA[2], preB[2];
  loadPre(0, preA);
  writePre(preA, 0);
  loadPre(1, preA);
  barrier();

  // steady state, unrolled x2 for static preA/preB roles:
  //   even i: issue pre(i+2) into preB; compute(i); write preA -> buf[(i+1)&1]
  //   odd  i: issue pre(i+2) into preA; compute(i); write preB -> buf[(i+1)&1]
#pragma unroll 1
  for (int it2 = 0; it2 < 16; it2++) {
    const int i0 = it2 * 2, i1 = i0 + 1;
    if (i0 + 2 < 32) loadPre(i0 + 2, preB);
    compute(i0);
    writePre(preA, ((i0 + 1) & 1) * 4352);
    barrier();
    if (i1 + 2 < 32) loadPre(i1 + 2, preA);
    compute(i1);
    if (i1 < 31) {
      writePre(preB, ((i1 + 1) & 1) * 4352);
      barrier();
    }
  }

  // epilogue: reduce l across the 16-lane k-groups once, then y = O / l
  float lr[4];
#pragma unroll
  for (int r2 = 0; r2 < 4; r2++) {
    float s = psum[r2];
#pragma unroll
    for (int d = 1; d < 16; d <<= 1) s += __shfl_xor(s, d);
    lr[r2] = s;
  }
#pragma unroll
  for (int nt = 0; nt < 4; nt++)
#pragma unroll
    for (int r2 = 0; r2 < 4; r2++) {
      const int row = q0 + lg * 4 + r2;
      yb[((size_t)(b * 1024 + row)) * 512 + h * 64 + nt * 16 + lm] = f2bf(o[nt][r2] / lr[r2]);
    }
}

// ---------------------------------------------------------------- launch
extern "C" void kernel_launch(void* const* d_in, const int* in_sizes, int n_in,
                              void* d_out, int out_size, void* d_ws, size_t ws_size,
                              hipStream_t stream) {
  const float* x    = (const float*)d_in[0];
  const float* bias = (const float*)d_in[1];
  const float* Wqkv = (const float*)d_in[2];
  const float* bqkv = (const float*)d_in[3];
  const float* Wo   = (const float*)d_in[4];
  const float* bo   = (const float*)d_in[5];
  float* out = (float*)d_out;

  char* p = (char*)d_ws;
  u16* xb    = (u16*)p; p += (size_t)8192 * 512 * 2;        // 8 MB
  u16* wqkvT = (u16*)p; p += (size_t)1536 * 512 * 2;        // 1.5 MB
  u16* woT   = (u16*)p; p += (size_t)512 * 512 * 2;         // 0.5 MB
  u16* qB    = (u16*)p; p += (size_t)8 * 8 * 1024 * 64 * 2; // 8 MB
  u16* kB    = (u16*)p; p += (size_t)8 * 8 * 1024 * 64 * 2; // 8 MB
  u16* vtB   = (u16*)p; p += (size_t)8 * 8 * 64 * 1024 * 2; // 8 MB
  u16* yB    = (u16*)p; p += (size_t)8192 * 512 * 2;        // 8 MB  (total ~44 MB)

  cvt_x_kernel<<<4096, 256, 0, stream>>>(x, xb);
  transp_kernel<<<dim3(48, 16), 256, 0, stream>>>(Wqkv, wqkvT, 1536);
  transp_kernel<<<dim3(16, 16), 256, 0, stream>>>(Wo, woT, 512);
  gemm_kernel<0, 128><<<dim3(12, 64), 256, 0, stream>>>(xb, wqkvT, bqkv, qB, kB, vtB, nullptr);
  attn_kernel<<<dim3(64, 8), 512, 0, stream>>>(qB, kB, vtB, bias, yB);
  gemm_kernel<1, 64><<<dim3(8, 64), 256, 0, stream>>>(yB, woT, bo, nullptr, nullptr, nullptr, out);
}